// Round 7
// baseline (285.217 us; speedup 1.0000x reference)
//
#include <hip/hip_runtime.h>
#include <stdint.h>

typedef _Float16 f16;
typedef __attribute__((ext_vector_type(8))) _Float16 f16x8;
typedef __attribute__((ext_vector_type(4))) float f32x4;

// ---------------- threefry2x32 (JAX partitionable, key=(0,42), counts=(0,i)) ----
// returns w0 ^ w1 (JAX xor-fold for 32-bit draws). rotl forced to v_alignbit_b32.
__device__ __forceinline__ uint32_t rotl1(uint32_t x, uint32_t n){
  return __builtin_amdgcn_alignbit(x, x, 32u - n);
}
__device__ __forceinline__ uint32_t tf_bits(uint32_t i){
  const uint32_t ks1 = 42u, ks2 = 0x1BD11BDAu ^ 42u;
  uint32_t x0 = 0u, x1 = i + 42u;
#define R4(a,b,c,d) \
  x0 += x1; x1 = rotl1(x1,a); x1 ^= x0; \
  x0 += x1; x1 = rotl1(x1,b); x1 ^= x0; \
  x0 += x1; x1 = rotl1(x1,c); x1 ^= x0; \
  x0 += x1; x1 = rotl1(x1,d); x1 ^= x0;
  R4(13,15,26,6)  x0 += ks1; x1 += ks2 + 1u;
  R4(17,29,16,24) x0 += ks2; x1 += 2u;         // ks0 = 0
  R4(13,15,26,6)               x1 += ks1 + 3u; // x0 += ks0 = +0
  R4(17,29,16,24) x0 += ks1; x1 += ks2 + 4u;
  R4(13,15,26,6)  x0 += ks2; x1 += 5u;         // ks0 = 0
#undef R4
  return x0 ^ x1;
}

// ---------------- K0: weight transposes (tiny) ----------------
// blocks 0..15: WqT, 16..31: WkT, 32..47: WvT  (f16 [64][1024], WT[c][k]=W[k][c])
// blocks 48..63: WoT (f16 [1024][64], WoT[n][k]=Wo[k][n])
__global__ __launch_bounds__(256) void wt_kernel(
    const float* __restrict__ Wq, const float* __restrict__ Wk,
    const float* __restrict__ Wv, const float* __restrict__ Wo,
    f16* __restrict__ WqT, f16* __restrict__ WkT,
    f16* __restrict__ WvT, f16* __restrict__ WoT)
{
  __shared__ __align__(16) f16 Tl[64][72];
  const int b = blockIdx.x, tid = threadIdx.x;
  const int which = b >> 4, t = b & 15;
  const float* src = which==0?Wq:(which==1?Wk:(which==2?Wv:Wo));
  const int rr = tid >> 2, cb = (tid & 3) * 16;
  if (which < 3){
    const float* s = src + (long)(t*64 + rr)*64 + cb;
    #pragma unroll
    for (int j=0;j<16;j++) Tl[cb+j][rr] = (f16)s[j];
  } else {
    const float* s = src + (long)rr*1024 + t*64 + cb;
    #pragma unroll
    for (int j=0;j<16;j++) Tl[cb+j][rr] = (f16)s[j];
  }
  __syncthreads();
  f16* dst = which==0?WqT:(which==1?WkT:(which==2?WvT:WoT));
  const int c = tid >> 2, kb = (tid & 3) * 16;
  if (which < 3){
    *(f16x8*)&dst[(long)c*1024 + t*64 + kb]     = *(const f16x8*)&Tl[c][kb];
    *(f16x8*)&dst[(long)c*1024 + t*64 + kb + 8] = *(const f16x8*)&Tl[c][kb+8];
  } else {
    *(f16x8*)&dst[(long)(t*64 + c)*64 + kb]     = *(const f16x8*)&Tl[c][kb];
    *(f16x8*)&dst[(long)(t*64 + c)*64 + kb + 8] = *(const f16x8*)&Tl[c][kb+8];
  }
}

// ---------------- K1: zero-LDS streaming projections ----------------
// 1536 blocks: which = bid>>9 (q/k/v), 64-row tile. A-frags direct from global
// (each wave's rows are private), WT B-frags direct from L2. No barriers.
__device__ __forceinline__ void proj_step(const float4* ab, const f16x8* wb, f32x4* acc){
  union { f16 h[8]; f16x8 v; } u0, u1;
  u0.h[0]=(f16)ab[0].x; u0.h[1]=(f16)ab[0].y; u0.h[2]=(f16)ab[0].z; u0.h[3]=(f16)ab[0].w;
  u0.h[4]=(f16)ab[1].x; u0.h[5]=(f16)ab[1].y; u0.h[6]=(f16)ab[1].z; u0.h[7]=(f16)ab[1].w;
  u1.h[0]=(f16)ab[2].x; u1.h[1]=(f16)ab[2].y; u1.h[2]=(f16)ab[2].z; u1.h[3]=(f16)ab[2].w;
  u1.h[4]=(f16)ab[3].x; u1.h[5]=(f16)ab[3].y; u1.h[6]=(f16)ab[3].z; u1.h[7]=(f16)ab[3].w;
  #pragma unroll
  for (int n=0;n<4;n++){
    acc[n] = __builtin_amdgcn_mfma_f32_16x16x32_f16(u0.v, wb[n*2],   acc[n], 0,0,0);
    acc[n] = __builtin_amdgcn_mfma_f32_16x16x32_f16(u1.v, wb[n*2+1], acc[n], 0,0,0);
  }
}

__global__ __launch_bounds__(256) void proj_kernel(
    const float* __restrict__ query, const float* __restrict__ keyp, const float* __restrict__ value,
    const f16* __restrict__ WqT, const f16* __restrict__ WkT, const f16* __restrict__ WvT,
    const float* __restrict__ bq, const float* __restrict__ bk, const float* __restrict__ bv,
    f16* __restrict__ qp, f16* __restrict__ kp, f16* __restrict__ vpT)
{
  const int bid = blockIdx.x;
  const int which = bid >> 9;           // 0..2
  const long m0 = (long)(bid & 511) * 64;
  const float* A    = which==0 ? query : (which==1 ? keyp : value);
  const f16*   WT   = which==0 ? WqT   : (which==1 ? WkT  : WvT);
  const float* bias = which==0 ? bq    : (which==1 ? bk   : bv);

  const int tid = threadIdx.x;
  const int lane = tid & 63, wave = tid >> 6;
  const int llo = lane & 15, lhi = lane >> 4;

  f32x4 acc[4];
  #pragma unroll
  for (int n=0;n<4;n++){
    float bb = bias[16*n + llo];
    acc[n][0]=bb; acc[n][1]=bb; acc[n][2]=bb; acc[n][3]=bb;
  }

  const float* arow = A + (m0 + wave*16 + llo)*1024 + lhi*8;
  const f16*   wrow = WT + (long)llo*1024 + lhi*8;

#define LOADA(k0, d) { \
    d[0] = *(const float4*)(arow + (k0)); \
    d[1] = *(const float4*)(arow + (k0) + 4); \
    d[2] = *(const float4*)(arow + (k0) + 32); \
    d[3] = *(const float4*)(arow + (k0) + 36); }
#define LOADW(k0, d) { \
    _Pragma("unroll") \
    for (int n=0;n<4;n++){ \
      d[n*2]   = *(const f16x8*)(wrow + n*16384 + (k0)); \
      d[n*2+1] = *(const f16x8*)(wrow + n*16384 + (k0) + 32); } }

  float4 a0[4], a1[4]; f16x8 w0[8], w1[8];
  LOADA(0, a0) LOADW(0, w0)
  #pragma unroll 1
  for (int it = 0; it < 16; it += 2){
    LOADA((it+1)*64, a1) LOADW((it+1)*64, w1)
    proj_step(a0, w0, acc);
    if (it + 2 < 16){ LOADA((it+2)*64, a0) LOADW((it+2)*64, w0) }
    proj_step(a1, w1, acc);
  }
#undef LOADA
#undef LOADW

  if (which < 2){
    const float scale = (which==0) ? 2.0f : 1.0f;   // fold dk=2.0 into q
    f16* dst = (which==0) ? qp : kp;
    #pragma unroll
    for (int n=0;n<4;n++)
      #pragma unroll
      for (int j=0;j<4;j++){
        long row = m0 + wave*16 + lhi*4 + j;
        dst[row*64 + 16*n + llo] = (f16)(acc[n][j]*scale);
      }
  } else {
    long row0 = m0 + wave*16 + lhi*4;
    long bh = row0 >> 11;
    long lr = row0 & 2047;
    #pragma unroll
    for (int n=0;n<4;n++){
      union { f16 h[4]; ushort4 u; } pk;
      #pragma unroll
      for (int j=0;j<4;j++) pk.h[j] = (f16)acc[n][j];
      *(ushort4*)&vpT[(bh*64 + 16*n + llo)*2048 + lr] = pk.u;
    }
  }
}

// ---------------- K2: flash attention with survivor-compacted threefry dropout
//                  + fused output projection (unchanged from round 6) ----------
__global__ __launch_bounds__(256) void flash_kernel(
    const f16* __restrict__ qp, const f16* __restrict__ kp, const f16* __restrict__ vpT,
    const f16* __restrict__ WoT, const float* __restrict__ bo, float* __restrict__ out)
{
  __shared__ __align__(16) f16 Klds[64][72];     // kv x dim; reused for O in epilogue
  __shared__ __align__(16) f16 Vlds[64][72];     // vdim x kv
  __shared__ __align__(16) f16 Plds[4][16][72];  // per-wave P (A-frag layout)
  __shared__ unsigned short Idl[4][1024];        // per-wave survivor id list
  const int tid = threadIdx.x;
  const int lane = tid & 63, wave = tid >> 6;
  const int llo = lane & 15, lhi = lane >> 4;
  const int bh = blockIdx.y;
  const int q0 = blockIdx.x * 64;

  const f16* qbase = qp + ((long)bh*2048 + q0 + wave*16 + llo)*64 + lhi*8;
  f16x8 qf0 = *(const f16x8*)qbase;
  f16x8 qf1 = *(const f16x8*)(qbase + 32);

  f32x4 O[4];
  float mrun[4], lrun[4];
  #pragma unroll
  for (int n=0;n<4;n++){ O[n][0]=0.f;O[n][1]=0.f;O[n][2]=0.f;O[n][3]=0.f; }
  #pragma unroll
  for (int j=0;j<4;j++){ mrun[j] = -__builtin_inff(); lrun[j]=0.f; }

  const int sr = tid >> 2;            // stage row 0..63
  const int sc = (tid & 3) * 16;      // stage col (f16)
  const f16* kbh = kp + (long)bh*2048*64;
  const f16* vbh = vpT + (long)bh*64*2048;
  uint32_t base_w = (uint32_t)((bh*2048 + q0 + wave*16)*2048);

  for (int kv0 = 0; kv0 < 2048; kv0 += 64, base_w += 64u){
    {
      const f16* src = kbh + (long)(kv0 + sr)*64 + sc;
      f16x8 t0 = *(const f16x8*)src;
      f16x8 t1 = *(const f16x8*)(src+8);
      *(f16x8*)&Klds[sr][sc]   = t0;
      *(f16x8*)&Klds[sr][sc+8] = t1;
      const f16* vsrc = vbh + (long)sr*2048 + kv0 + sc;
      f16x8 u0 = *(const f16x8*)vsrc;
      f16x8 u1 = *(const f16x8*)(vsrc+8);
      *(f16x8*)&Vlds[sr][sc]   = u0;
      *(f16x8*)&Vlds[sr][sc+8] = u1;
    }
    __syncthreads();

    f32x4 s[4];
    #pragma unroll
    for (int n=0;n<4;n++){ s[n][0]=0.f;s[n][1]=0.f;s[n][2]=0.f;s[n][3]=0.f; }
    #pragma unroll
    for (int n=0;n<4;n++){
      f16x8 kf0 = *(const f16x8*)&Klds[16*n+llo][lhi*8];
      s[n] = __builtin_amdgcn_mfma_f32_16x16x32_f16(qf0, kf0, s[n], 0,0,0);
      f16x8 kf1 = *(const f16x8*)&Klds[16*n+llo][32+lhi*8];
      s[n] = __builtin_amdgcn_mfma_f32_16x16x32_f16(qf1, kf1, s[n], 0,0,0);
    }
    float pmax[4];
    #pragma unroll
    for (int j=0;j<4;j++)
      pmax[j] = fmaxf(fmaxf(s[0][j],s[1][j]), fmaxf(s[2][j],s[3][j]));
    #pragma unroll
    for (int off=1; off<16; off<<=1){
      #pragma unroll
      for (int j=0;j<4;j++) pmax[j] = fmaxf(pmax[j], __shfl_xor(pmax[j], off));
    }
    float esc[4];
    #pragma unroll
    for (int j=0;j<4;j++){
      float mnew = fmaxf(mrun[j], pmax[j]);
      esc[j] = __expf(mrun[j] - mnew);
      mrun[j] = mnew;
    }
    float p[4][4]; float lsum[4] = {0.f,0.f,0.f,0.f};
    #pragma unroll
    for (int n=0;n<4;n++)
      #pragma unroll
      for (int j=0;j<4;j++){
        p[n][j] = __expf(s[n][j] - mrun[j]);
        lsum[j] += p[n][j];
      }
    #pragma unroll
    for (int off=1; off<16; off<<=1){
      #pragma unroll
      for (int j=0;j<4;j++) lsum[j] += __shfl_xor(lsum[j], off);
    }
    #pragma unroll
    for (int j=0;j<4;j++) lrun[j] = lrun[j]*esc[j] + lsum[j];
    #pragma unroll
    for (int n=0;n<4;n++)
      #pragma unroll
      for (int j=0;j<4;j++) O[n][j] *= esc[j];

    // ---- dropout via survivor compaction ----
    uint32_t cnt = 0;
    #pragma unroll
    for (int j=0;j<4;j++){
      #pragma unroll
      for (int n=0;n<4;n++){
        float pm = p[n][j]*(1.0f/0.9f);
        bool surv = pm > 0x1.0p-25f;            // (f16)pm != 0
        Plds[wave][lhi*4+j][16*n+llo] = (f16)pm;
        unsigned long long mk = __ballot(surv);
        if (mk){
          uint32_t pre = __builtin_amdgcn_mbcnt_hi((uint32_t)(mk>>32),
                         __builtin_amdgcn_mbcnt_lo((uint32_t)mk, 0u));
          if (surv)
            Idl[wave][cnt + pre] = (unsigned short)((j<<8)|(n<<6)|lane);
          cnt += (uint32_t)__builtin_popcountll(mk);
        }
      }
    }
    for (uint32_t pb = 0; pb < cnt; pb += 64){
      uint32_t idx = pb + (uint32_t)lane;
      if (idx < cnt){
        uint32_t id = (uint32_t)Idl[wave][idx];
        uint32_t jj = (id>>8)&3u, nn = (id>>6)&3u, ln = id & 63u;
        uint32_t i = base_w + (ln>>4)*8192u + jj*2048u + nn*16u + (ln&15u);
        uint32_t bits = tf_bits(i);
        if (bits >= 0xE6666600u)                 // uniform(bits) >= 0.9 -> drop
          Plds[wave][(ln>>4)*4+jj][16*nn+(ln&15u)] = (f16)0;
      }
    }

    f16x8 pa0 = *(const f16x8*)&Plds[wave][llo][lhi*8];
    f16x8 pa1 = *(const f16x8*)&Plds[wave][llo][32+lhi*8];
    #pragma unroll
    for (int n=0;n<4;n++){
      f16x8 vf0 = *(const f16x8*)&Vlds[16*n+llo][lhi*8];
      O[n] = __builtin_amdgcn_mfma_f32_16x16x32_f16(pa0, vf0, O[n], 0,0,0);
      f16x8 vf1 = *(const f16x8*)&Vlds[16*n+llo][32+lhi*8];
      O[n] = __builtin_amdgcn_mfma_f32_16x16x32_f16(pa1, vf1, O[n], 0,0,0);
    }
    __syncthreads();
  }

  // ---- fused epilogue: out[rows] = (O/l) @ Wo + bo, O staged f16 in Klds ----
  float rl[4];
  #pragma unroll
  for (int j=0;j<4;j++) rl[j] = 1.0f / lrun[j];
  #pragma unroll
  for (int n=0;n<4;n++)
    #pragma unroll
    for (int j=0;j<4;j++)
      Klds[wave*16 + lhi*4 + j][16*n + llo] = (f16)(O[n][j]*rl[j]);
  __syncthreads();

  f16x8 af0 = *(const f16x8*)&Klds[wave*16 + llo][lhi*8];
  f16x8 af1 = *(const f16x8*)&Klds[wave*16 + llo][32 + lhi*8];
  const long robase = (long)bh*2048 + q0 + wave*16 + lhi*4;
  for (int n0 = 0; n0 < 1024; n0 += 16){
    f16x8 b0 = *(const f16x8*)&WoT[(long)(n0+llo)*64 + lhi*8];
    f16x8 b1 = *(const f16x8*)&WoT[(long)(n0+llo)*64 + 32 + lhi*8];
    float bb = bo[n0+llo];
    f32x4 c; c[0]=bb; c[1]=bb; c[2]=bb; c[3]=bb;
    c = __builtin_amdgcn_mfma_f32_16x16x32_f16(af0, b0, c, 0,0,0);
    c = __builtin_amdgcn_mfma_f32_16x16x32_f16(af1, b1, c, 0,0,0);
    #pragma unroll
    for (int j=0;j<4;j++)
      out[(robase + j)*1024 + n0 + llo] = c[j];
  }
}

extern "C" void kernel_launch(void* const* d_in, const int* in_sizes, int n_in,
                              void* d_out, int out_size, void* d_ws, size_t ws_size,
                              hipStream_t stream){
  const float* query = (const float*)d_in[0];
  const float* key   = (const float*)d_in[1];
  const float* value = (const float*)d_in[2];
  const float* Wq = (const float*)d_in[3];
  const float* bq = (const float*)d_in[4];
  const float* Wk = (const float*)d_in[5];
  const float* bk = (const float*)d_in[6];
  const float* Wv = (const float*)d_in[7];
  const float* bv = (const float*)d_in[8];
  const float* Wo = (const float*)d_in[9];
  const float* bo = (const float*)d_in[10];
  float* out = (float*)d_out;

  char* ws = (char*)d_ws;
  f16* qp   = (f16*)(ws);                               // 4 MiB
  f16* kp   = (f16*)(ws + ((size_t)4<<20));             // 4 MiB
  f16* vpT  = (f16*)(ws + ((size_t)8<<20));             // 4 MiB
  f16* WoT  = (f16*)(ws + ((size_t)20<<20));            // 128 KiB
  f16* WqT  = (f16*)(ws + ((size_t)21<<20));            // 128 KiB
  f16* WkT  = (f16*)(ws + ((size_t)21<<20) + (256<<10));
  f16* WvT  = (f16*)(ws + ((size_t)21<<20) + (512<<10));

  wt_kernel<<<dim3(64), dim3(256), 0, stream>>>(Wq,Wk,Wv,Wo,WqT,WkT,WvT,WoT);
  proj_kernel<<<dim3(1536), dim3(256), 0, stream>>>(
      query,key,value,WqT,WkT,WvT,bq,bk,bv,qp,kp,vpT);
  flash_kernel<<<dim3(32,16), dim3(256), 0, stream>>>(qp,kp,vpT,WoT,bo,out);
}

// Round 8
// 279.122 us; speedup vs baseline: 1.0218x; 1.0218x over previous
//
#include <hip/hip_runtime.h>
#include <stdint.h>

typedef _Float16 f16;
typedef __attribute__((ext_vector_type(8))) _Float16 f16x8;
typedef __attribute__((ext_vector_type(4))) float f32x4;

// ---------------- threefry2x32 (JAX partitionable, key=(0,42), counts=(0,i)) ----
// returns w0 ^ w1 (JAX xor-fold for 32-bit draws). rotl forced to v_alignbit_b32.
__device__ __forceinline__ uint32_t rotl1(uint32_t x, uint32_t n){
  return __builtin_amdgcn_alignbit(x, x, 32u - n);
}
__device__ __forceinline__ uint32_t tf_bits(uint32_t i){
  const uint32_t ks1 = 42u, ks2 = 0x1BD11BDAu ^ 42u;
  uint32_t x0 = 0u, x1 = i + 42u;
#define R4(a,b,c,d) \
  x0 += x1; x1 = rotl1(x1,a); x1 ^= x0; \
  x0 += x1; x1 = rotl1(x1,b); x1 ^= x0; \
  x0 += x1; x1 = rotl1(x1,c); x1 ^= x0; \
  x0 += x1; x1 = rotl1(x1,d); x1 ^= x0;
  R4(13,15,26,6)  x0 += ks1; x1 += ks2 + 1u;
  R4(17,29,16,24) x0 += ks2; x1 += 2u;         // ks0 = 0
  R4(13,15,26,6)               x1 += ks1 + 3u; // x0 += ks0 = +0
  R4(17,29,16,24) x0 += ks1; x1 += ks2 + 4u;
  R4(13,15,26,6)  x0 += ks2; x1 += 5u;         // ks0 = 0
#undef R4
  return x0 ^ x1;
}

// ---------------- K0: weight transposes (tiny) ----------------
// blocks 0..15: WqT, 16..31: WkT, 32..47: WvT  (f16 [64][1024], WT[c][k]=W[k][c])
// blocks 48..63: WoT (f16 [1024][64], WoT[n][k]=Wo[k][n])
__global__ __launch_bounds__(256) void wt_kernel(
    const float* __restrict__ Wq, const float* __restrict__ Wk,
    const float* __restrict__ Wv, const float* __restrict__ Wo,
    f16* __restrict__ WqT, f16* __restrict__ WkT,
    f16* __restrict__ WvT, f16* __restrict__ WoT)
{
  __shared__ __align__(16) f16 Tl[64][72];
  const int b = blockIdx.x, tid = threadIdx.x;
  const int which = b >> 4, t = b & 15;
  const float* src = which==0?Wq:(which==1?Wk:(which==2?Wv:Wo));
  const int rr = tid >> 2, cb = (tid & 3) * 16;
  if (which < 3){
    const float* s = src + (long)(t*64 + rr)*64 + cb;
    #pragma unroll
    for (int j=0;j<16;j++) Tl[cb+j][rr] = (f16)s[j];
  } else {
    const float* s = src + (long)rr*1024 + t*64 + cb;
    #pragma unroll
    for (int j=0;j<16;j++) Tl[cb+j][rr] = (f16)s[j];
  }
  __syncthreads();
  f16* dst = which==0?WqT:(which==1?WkT:(which==2?WvT:WoT));
  const int c = tid >> 2, kb = (tid & 3) * 16;
  if (which < 3){
    *(f16x8*)&dst[(long)c*1024 + t*64 + kb]     = *(const f16x8*)&Tl[c][kb];
    *(f16x8*)&dst[(long)c*1024 + t*64 + kb + 8] = *(const f16x8*)&Tl[c][kb+8];
  } else {
    *(f16x8*)&dst[(long)(t*64 + c)*64 + kb]     = *(const f16x8*)&Tl[c][kb];
    *(f16x8*)&dst[(long)(t*64 + c)*64 + kb + 8] = *(const f16x8*)&Tl[c][kb+8];
  }
}

// ---------------- K1: projections — LDS-dbuf A staging + reg W from L2 --------
// 1536 blocks; which = bid>>9 (q/k/v); 64-row tile; K-step 64.
// Per iter: Wregs(t) [L2,16B] -> Aregs(t+1) [HBM,64B/lane] -> MFMA(t)
// (waits only the older W loads) -> cvt+ds_write A(t+1) -> ONE barrier.
__global__ __launch_bounds__(256) void proj_kernel(
    const float* __restrict__ query, const float* __restrict__ keyp, const float* __restrict__ value,
    const f16* __restrict__ WqT, const f16* __restrict__ WkT, const f16* __restrict__ WvT,
    const float* __restrict__ bq, const float* __restrict__ bk, const float* __restrict__ bv,
    f16* __restrict__ qp, f16* __restrict__ kp, f16* __restrict__ vpT)
{
  __shared__ __align__(16) f16 Alds[2][64][72];   // 144B stride: 2-way bank alias (free)
  const int bid = blockIdx.x;
  const int which = bid >> 9;           // 0..2
  const long m0 = (long)(bid & 511) * 64;
  const float* A    = which==0 ? query : (which==1 ? keyp : value);
  const f16*   WT   = which==0 ? WqT   : (which==1 ? WkT  : WvT);
  const float* bias = which==0 ? bq    : (which==1 ? bk   : bv);

  const int tid = threadIdx.x;
  const int lane = tid & 63, wave = tid >> 6;
  const int llo = lane & 15, lhi = lane >> 4;

  f32x4 acc[4];
  #pragma unroll
  for (int n=0;n<4;n++){
    float bb = bias[16*n + llo];
    acc[n][0]=bb; acc[n][1]=bb; acc[n][2]=bb; acc[n][3]=bb;
  }

  // A staging: row = tid>>2 (0..63), 16 consecutive floats per lane (64B)
  const int ar = tid >> 2;
  const int ac = (tid & 3) * 16;
  const float* abase = A + (m0 + ar)*1024 + ac;
  // W fragments: rows 16n+llo of WT, 16B per frag
  const f16* wbase = WT + (long)llo*1024 + lhi*8;

  float4 st[4];
  #pragma unroll
  for (int q=0;q<4;q++) st[q] = *(const float4*)(abase + q*4);
  {
    union { f16 h[16]; f16x8 v[2]; } u;
    #pragma unroll
    for (int q=0;q<4;q++){
      u.h[q*4+0]=(f16)st[q].x; u.h[q*4+1]=(f16)st[q].y;
      u.h[q*4+2]=(f16)st[q].z; u.h[q*4+3]=(f16)st[q].w;
    }
    *(f16x8*)&Alds[0][ar][ac]   = u.v[0];
    *(f16x8*)&Alds[0][ar][ac+8] = u.v[1];
  }
  __syncthreads();

  int buf = 0;
  #pragma unroll 1
  for (int t = 0; t < 16; ++t){
    // W(t) first (older in vmcnt queue -> MFMA wait doesn't drain A(t+1))
    f16x8 wreg[8];
    {
      const f16* wk0 = wbase + t*64;
      #pragma unroll
      for (int n=0;n<4;n++){
        wreg[n*2]   = *(const f16x8*)(wk0 + n*16384);
        wreg[n*2+1] = *(const f16x8*)(wk0 + n*16384 + 32);
      }
    }
    // A(t+1) issue (newer; stays in flight through MFMA)
    if (t < 15){
      #pragma unroll
      for (int q=0;q<4;q++) st[q] = *(const float4*)(abase + (t+1)*64 + q*4);
    }
    // MFMA(t): A-frags from LDS, W from regs
    f16x8 af0 = *(const f16x8*)&Alds[buf][wave*16 + llo][lhi*8];
    f16x8 af1 = *(const f16x8*)&Alds[buf][wave*16 + llo][32 + lhi*8];
    #pragma unroll
    for (int n=0;n<4;n++){
      acc[n] = __builtin_amdgcn_mfma_f32_16x16x32_f16(af0, wreg[n*2],   acc[n], 0,0,0);
      acc[n] = __builtin_amdgcn_mfma_f32_16x16x32_f16(af1, wreg[n*2+1], acc[n], 0,0,0);
    }
    // cvt + stage A(t+1) into the other buffer
    if (t < 15){
      union { f16 h[16]; f16x8 v[2]; } u;
      #pragma unroll
      for (int q=0;q<4;q++){
        u.h[q*4+0]=(f16)st[q].x; u.h[q*4+1]=(f16)st[q].y;
        u.h[q*4+2]=(f16)st[q].z; u.h[q*4+3]=(f16)st[q].w;
      }
      *(f16x8*)&Alds[buf^1][ar][ac]   = u.v[0];
      *(f16x8*)&Alds[buf^1][ar][ac+8] = u.v[1];
      __syncthreads();
    }
    buf ^= 1;
  }

  if (which < 2){
    const float scale = (which==0) ? 2.0f : 1.0f;   // fold dk=2.0 into q
    f16* dst = (which==0) ? qp : kp;
    #pragma unroll
    for (int n=0;n<4;n++)
      #pragma unroll
      for (int j=0;j<4;j++){
        long row = m0 + wave*16 + lhi*4 + j;
        dst[row*64 + 16*n + llo] = (f16)(acc[n][j]*scale);
      }
  } else {
    long row0 = m0 + wave*16 + lhi*4;
    long bh = row0 >> 11;
    long lr = row0 & 2047;
    #pragma unroll
    for (int n=0;n<4;n++){
      union { f16 h[4]; ushort4 u; } pk;
      #pragma unroll
      for (int j=0;j<4;j++) pk.h[j] = (f16)acc[n][j];
      *(ushort4*)&vpT[(bh*64 + 16*n + llo)*2048 + lr] = pk.u;
    }
  }
}

// ---------------- K2: flash attention with survivor-compacted threefry dropout
//                  + fused output projection (unchanged) ----------
__global__ __launch_bounds__(256) void flash_kernel(
    const f16* __restrict__ qp, const f16* __restrict__ kp, const f16* __restrict__ vpT,
    const f16* __restrict__ WoT, const float* __restrict__ bo, float* __restrict__ out)
{
  __shared__ __align__(16) f16 Klds[64][72];     // kv x dim; reused for O in epilogue
  __shared__ __align__(16) f16 Vlds[64][72];     // vdim x kv
  __shared__ __align__(16) f16 Plds[4][16][72];  // per-wave P (A-frag layout)
  __shared__ unsigned short Idl[4][1024];        // per-wave survivor id list
  const int tid = threadIdx.x;
  const int lane = tid & 63, wave = tid >> 6;
  const int llo = lane & 15, lhi = lane >> 4;
  const int bh = blockIdx.y;
  const int q0 = blockIdx.x * 64;

  const f16* qbase = qp + ((long)bh*2048 + q0 + wave*16 + llo)*64 + lhi*8;
  f16x8 qf0 = *(const f16x8*)qbase;
  f16x8 qf1 = *(const f16x8*)(qbase + 32);

  f32x4 O[4];
  float mrun[4], lrun[4];
  #pragma unroll
  for (int n=0;n<4;n++){ O[n][0]=0.f;O[n][1]=0.f;O[n][2]=0.f;O[n][3]=0.f; }
  #pragma unroll
  for (int j=0;j<4;j++){ mrun[j] = -__builtin_inff(); lrun[j]=0.f; }

  const int sr = tid >> 2;            // stage row 0..63
  const int sc = (tid & 3) * 16;      // stage col (f16)
  const f16* kbh = kp + (long)bh*2048*64;
  const f16* vbh = vpT + (long)bh*64*2048;
  uint32_t base_w = (uint32_t)((bh*2048 + q0 + wave*16)*2048);

  for (int kv0 = 0; kv0 < 2048; kv0 += 64, base_w += 64u){
    {
      const f16* src = kbh + (long)(kv0 + sr)*64 + sc;
      f16x8 t0 = *(const f16x8*)src;
      f16x8 t1 = *(const f16x8*)(src+8);
      *(f16x8*)&Klds[sr][sc]   = t0;
      *(f16x8*)&Klds[sr][sc+8] = t1;
      const f16* vsrc = vbh + (long)sr*2048 + kv0 + sc;
      f16x8 u0 = *(const f16x8*)vsrc;
      f16x8 u1 = *(const f16x8*)(vsrc+8);
      *(f16x8*)&Vlds[sr][sc]   = u0;
      *(f16x8*)&Vlds[sr][sc+8] = u1;
    }
    __syncthreads();

    f32x4 s[4];
    #pragma unroll
    for (int n=0;n<4;n++){ s[n][0]=0.f;s[n][1]=0.f;s[n][2]=0.f;s[n][3]=0.f; }
    #pragma unroll
    for (int n=0;n<4;n++){
      f16x8 kf0 = *(const f16x8*)&Klds[16*n+llo][lhi*8];
      s[n] = __builtin_amdgcn_mfma_f32_16x16x32_f16(qf0, kf0, s[n], 0,0,0);
      f16x8 kf1 = *(const f16x8*)&Klds[16*n+llo][32+lhi*8];
      s[n] = __builtin_amdgcn_mfma_f32_16x16x32_f16(qf1, kf1, s[n], 0,0,0);
    }
    float pmax[4];
    #pragma unroll
    for (int j=0;j<4;j++)
      pmax[j] = fmaxf(fmaxf(s[0][j],s[1][j]), fmaxf(s[2][j],s[3][j]));
    #pragma unroll
    for (int off=1; off<16; off<<=1){
      #pragma unroll
      for (int j=0;j<4;j++) pmax[j] = fmaxf(pmax[j], __shfl_xor(pmax[j], off));
    }
    float esc[4];
    #pragma unroll
    for (int j=0;j<4;j++){
      float mnew = fmaxf(mrun[j], pmax[j]);
      esc[j] = __expf(mrun[j] - mnew);
      mrun[j] = mnew;
    }
    float p[4][4]; float lsum[4] = {0.f,0.f,0.f,0.f};
    #pragma unroll
    for (int n=0;n<4;n++)
      #pragma unroll
      for (int j=0;j<4;j++){
        p[n][j] = __expf(s[n][j] - mrun[j]);
        lsum[j] += p[n][j];
      }
    #pragma unroll
    for (int off=1; off<16; off<<=1){
      #pragma unroll
      for (int j=0;j<4;j++) lsum[j] += __shfl_xor(lsum[j], off);
    }
    #pragma unroll
    for (int j=0;j<4;j++) lrun[j] = lrun[j]*esc[j] + lsum[j];
    #pragma unroll
    for (int n=0;n<4;n++)
      #pragma unroll
      for (int j=0;j<4;j++) O[n][j] *= esc[j];

    // ---- dropout via survivor compaction ----
    uint32_t cnt = 0;
    #pragma unroll
    for (int j=0;j<4;j++){
      #pragma unroll
      for (int n=0;n<4;n++){
        float pm = p[n][j]*(1.0f/0.9f);
        bool surv = pm > 0x1.0p-25f;            // (f16)pm != 0
        Plds[wave][lhi*4+j][16*n+llo] = (f16)pm;
        unsigned long long mk = __ballot(surv);
        if (mk){
          uint32_t pre = __builtin_amdgcn_mbcnt_hi((uint32_t)(mk>>32),
                         __builtin_amdgcn_mbcnt_lo((uint32_t)mk, 0u));
          if (surv)
            Idl[wave][cnt + pre] = (unsigned short)((j<<8)|(n<<6)|lane);
          cnt += (uint32_t)__builtin_popcountll(mk);
        }
      }
    }
    for (uint32_t pb = 0; pb < cnt; pb += 64){
      uint32_t idx = pb + (uint32_t)lane;
      if (idx < cnt){
        uint32_t id = (uint32_t)Idl[wave][idx];
        uint32_t jj = (id>>8)&3u, nn = (id>>6)&3u, ln = id & 63u;
        uint32_t i = base_w + (ln>>4)*8192u + jj*2048u + nn*16u + (ln&15u);
        uint32_t bits = tf_bits(i);
        if (bits >= 0xE6666600u)                 // uniform(bits) >= 0.9 -> drop
          Plds[wave][(ln>>4)*4+jj][16*nn+(ln&15u)] = (f16)0;
      }
    }

    f16x8 pa0 = *(const f16x8*)&Plds[wave][llo][lhi*8];
    f16x8 pa1 = *(const f16x8*)&Plds[wave][llo][32+lhi*8];
    #pragma unroll
    for (int n=0;n<4;n++){
      f16x8 vf0 = *(const f16x8*)&Vlds[16*n+llo][lhi*8];
      O[n] = __builtin_amdgcn_mfma_f32_16x16x32_f16(pa0, vf0, O[n], 0,0,0);
      f16x8 vf1 = *(const f16x8*)&Vlds[16*n+llo][32+lhi*8];
      O[n] = __builtin_amdgcn_mfma_f32_16x16x32_f16(pa1, vf1, O[n], 0,0,0);
    }
    __syncthreads();
  }

  // ---- fused epilogue: out[rows] = (O/l) @ Wo + bo, O staged f16 in Klds ----
  float rl[4];
  #pragma unroll
  for (int j=0;j<4;j++) rl[j] = 1.0f / lrun[j];
  #pragma unroll
  for (int n=0;n<4;n++)
    #pragma unroll
    for (int j=0;j<4;j++)
      Klds[wave*16 + lhi*4 + j][16*n + llo] = (f16)(O[n][j]*rl[j]);
  __syncthreads();

  f16x8 af0 = *(const f16x8*)&Klds[wave*16 + llo][lhi*8];
  f16x8 af1 = *(const f16x8*)&Klds[wave*16 + llo][32 + lhi*8];
  const long robase = (long)bh*2048 + q0 + wave*16 + lhi*4;
  for (int n0 = 0; n0 < 1024; n0 += 16){
    f16x8 b0 = *(const f16x8*)&WoT[(long)(n0+llo)*64 + lhi*8];
    f16x8 b1 = *(const f16x8*)&WoT[(long)(n0+llo)*64 + 32 + lhi*8];
    float bb = bo[n0+llo];
    f32x4 c; c[0]=bb; c[1]=bb; c[2]=bb; c[3]=bb;
    c = __builtin_amdgcn_mfma_f32_16x16x32_f16(af0, b0, c, 0,0,0);
    c = __builtin_amdgcn_mfma_f32_16x16x32_f16(af1, b1, c, 0,0,0);
    #pragma unroll
    for (int j=0;j<4;j++)
      out[(robase + j)*1024 + n0 + llo] = c[j];
  }
}

extern "C" void kernel_launch(void* const* d_in, const int* in_sizes, int n_in,
                              void* d_out, int out_size, void* d_ws, size_t ws_size,
                              hipStream_t stream){
  const float* query = (const float*)d_in[0];
  const float* key   = (const float*)d_in[1];
  const float* value = (const float*)d_in[2];
  const float* Wq = (const float*)d_in[3];
  const float* bq = (const float*)d_in[4];
  const float* Wk = (const float*)d_in[5];
  const float* bk = (const float*)d_in[6];
  const float* Wv = (const float*)d_in[7];
  const float* bv = (const float*)d_in[8];
  const float* Wo = (const float*)d_in[9];
  const float* bo = (const float*)d_in[10];
  float* out = (float*)d_out;

  char* ws = (char*)d_ws;
  f16* qp   = (f16*)(ws);                               // 4 MiB
  f16* kp   = (f16*)(ws + ((size_t)4<<20));             // 4 MiB
  f16* vpT  = (f16*)(ws + ((size_t)8<<20));             // 4 MiB
  f16* WoT  = (f16*)(ws + ((size_t)20<<20));            // 128 KiB
  f16* WqT  = (f16*)(ws + ((size_t)21<<20));            // 128 KiB
  f16* WkT  = (f16*)(ws + ((size_t)21<<20) + (256<<10));
  f16* WvT  = (f16*)(ws + ((size_t)21<<20) + (512<<10));

  wt_kernel<<<dim3(64), dim3(256), 0, stream>>>(Wq,Wk,Wv,Wo,WqT,WkT,WvT,WoT);
  proj_kernel<<<dim3(1536), dim3(256), 0, stream>>>(
      query,key,value,WqT,WkT,WvT,bq,bk,bv,qp,kp,vpT);
  flash_kernel<<<dim3(32,16), dim3(256), 0, stream>>>(qp,kp,vpT,WoT,bo,out);
}

// Round 9
// 264.327 us; speedup vs baseline: 1.0790x; 1.0560x over previous
//
#include <hip/hip_runtime.h>
#include <stdint.h>

typedef _Float16 f16;
typedef __attribute__((ext_vector_type(8))) _Float16 f16x8;
typedef __attribute__((ext_vector_type(4))) float f32x4;

// ---------------- threefry2x32 (JAX partitionable, key=(0,42), counts=(0,i)) ----
// returns w0 ^ w1 (JAX xor-fold for 32-bit draws). rotl forced to v_alignbit_b32.
__device__ __forceinline__ uint32_t rotl1(uint32_t x, uint32_t n){
  return __builtin_amdgcn_alignbit(x, x, 32u - n);
}
__device__ __forceinline__ uint32_t tf_bits(uint32_t i){
  const uint32_t ks1 = 42u, ks2 = 0x1BD11BDAu ^ 42u;
  uint32_t x0 = 0u, x1 = i + 42u;
#define R4(a,b,c,d) \
  x0 += x1; x1 = rotl1(x1,a); x1 ^= x0; \
  x0 += x1; x1 = rotl1(x1,b); x1 ^= x0; \
  x0 += x1; x1 = rotl1(x1,c); x1 ^= x0; \
  x0 += x1; x1 = rotl1(x1,d); x1 ^= x0;
  R4(13,15,26,6)  x0 += ks1; x1 += ks2 + 1u;
  R4(17,29,16,24) x0 += ks2; x1 += 2u;         // ks0 = 0
  R4(13,15,26,6)               x1 += ks1 + 3u; // x0 += ks0 = +0
  R4(17,29,16,24) x0 += ks1; x1 += ks2 + 4u;
  R4(13,15,26,6)  x0 += ks2; x1 += 5u;         // ks0 = 0
#undef R4
  return x0 ^ x1;
}

// ---------------- K0: weight repack ----------------
// blocks 0..47 (m = b>>4 in {q,k,v}, t = b&15): pack W[1024][64] into MFMA
// fragment order WfM[((t*8 + f)*64 + lane)*8 + e], f = n*2+h:
//   = W[(t*64 + h*32 + (lane>>4)*8 + e)*64 + n*16 + (lane&15)]
// -> proj's W loads become perfectly contiguous 1KB per wave instruction.
// blocks 48..63: WoT[n][k] = Wo[k][n]  (f16 [1024][64], for flash epilogue)
__global__ __launch_bounds__(256) void wt_kernel(
    const float* __restrict__ Wq, const float* __restrict__ Wk,
    const float* __restrict__ Wv, const float* __restrict__ Wo,
    f16* __restrict__ WqF, f16* __restrict__ WkF,
    f16* __restrict__ WvF, f16* __restrict__ WoT)
{
  const int b = blockIdx.x, tid = threadIdx.x;
  const int which = b >> 4, t = b & 15;
  const int lane = tid & 63, wave = tid >> 6;

  if (which < 3){
    const float* W = which==0 ? Wq : (which==1 ? Wk : Wv);
    f16* Wf        = which==0 ? WqF : (which==1 ? WkF : WvF);
    const int lhi = lane >> 4, llo = lane & 15;
    #pragma unroll
    for (int ff = 0; ff < 2; ++ff){
      const int f = wave + ff*4;         // 0..7
      const int n = f >> 1, h = f & 1;
      union { f16 h8[8]; f16x8 v; } pk;
      #pragma unroll
      for (int e = 0; e < 8; ++e)
        pk.h8[e] = (f16)W[(long)(t*64 + h*32 + lhi*8 + e)*64 + n*16 + llo];
      *(f16x8*)&Wf[((long)(t*8 + f)*64 + lane)*8] = pk.v;
    }
    return;
  }

  // WoT
  __shared__ __align__(16) f16 Tl[64][72];
  const int rr = tid >> 2, cb = (tid & 3) * 16;
  const float* s = Wo + (long)rr*1024 + t*64 + cb;
  #pragma unroll
  for (int j=0;j<16;j++) Tl[cb+j][rr] = (f16)s[j];
  __syncthreads();
  const int c = tid >> 2, kb = (tid & 3) * 16;
  *(f16x8*)&WoT[(long)(t*64 + c)*64 + kb]     = *(const f16x8*)&Tl[c][kb];
  *(f16x8*)&WoT[(long)(t*64 + c)*64 + kb + 8] = *(const f16x8*)&Tl[c][kb+8];
}

// ---------------- K1: barrier-free wave-private streaming projections --------
// 1536 blocks; which = bid>>9 (q/k/v); 64-row tile; K-step 64; 16 iters.
// Wave w owns rows [16w,16w+16): stages them itself, reads only them -> NO
// __syncthreads in the loop (no vmcnt drain). A prefetch 2 iters ahead in regs.
// Per iter: Wfrag(t) 8x16B contiguous -> A(t+2) 4x16B (4-row footprint) ->
// MFMA (vmcnt waits W only) -> ds_write A(t+1) (already retired).
__global__ __launch_bounds__(256) void proj_kernel(
    const float* __restrict__ query, const float* __restrict__ keyp, const float* __restrict__ value,
    const f16* __restrict__ WqF, const f16* __restrict__ WkF, const f16* __restrict__ WvF,
    const float* __restrict__ bq, const float* __restrict__ bk, const float* __restrict__ bv,
    f16* __restrict__ qp, f16* __restrict__ kp, f16* __restrict__ vpT)
{
  __shared__ __align__(16) f16 Alds[2][64][72];   // 144B row stride (2-way alias: free)
  const int bid = blockIdx.x;
  const int which = bid >> 9;           // 0..2
  const long m0 = (long)(bid & 511) * 64;
  const float* A    = which==0 ? query : (which==1 ? keyp : value);
  const f16*   WF   = which==0 ? WqF   : (which==1 ? WkF  : WvF);
  const float* bias = which==0 ? bq    : (which==1 ? bk   : bv);

  const int tid = threadIdx.x;
  const int lane = tid & 63, wave = tid >> 6;
  const int llo = lane & 15, lhi = lane >> 4;

  f32x4 acc[4];
  #pragma unroll
  for (int n=0;n<4;n++){
    float bb = bias[16*n + llo];
    acc[n][0]=bb; acc[n][1]=bb; acc[n][2]=bb; acc[n][3]=bb;
  }

  // A staging (wave-private rows): load q=0..3 -> row 16w+q*4+(lane>>4),
  // 16B contiguous at float col (lane&15)*4 of the 64-float K-slice.
  const int rq = lane >> 4;            // 0..3
  const int cf = (lane & 15) * 4;      // float col in slice
  const float* abase = A + (m0 + wave*16)*1024 + cf;
  const f16* wbase = WF + (size_t)lane*8;

#define LOADA(t, d) { _Pragma("unroll") \
    for (int q=0;q<4;q++) d[q] = *(const float4*)(abase + (size_t)(q*4+rq)*1024 + (size_t)(t)*64); }
#define STOREA(bf, d) { _Pragma("unroll") \
    for (int q=0;q<4;q++){ \
      union { f16 h[4]; unsigned long long u; } pk; \
      pk.h[0]=(f16)d[q].x; pk.h[1]=(f16)d[q].y; pk.h[2]=(f16)d[q].z; pk.h[3]=(f16)d[q].w; \
      *(unsigned long long*)&Alds[bf][wave*16 + q*4 + rq][cf] = pk.u; } }

  float4 s0[4], s1[4];
  LOADA(0, s0)
  STOREA(0, s0)          // one-time vmcnt(0) stall
  LOADA(1, s1)

#define PROJ_ITER(t, SLD, SST) { \
    f16x8 wf[8]; \
    _Pragma("unroll") \
    for (int f=0; f<8; f++) wf[f] = *(const f16x8*)(wbase + (size_t)((t)*8+f)*512); \
    if ((t) < 14) { LOADA((t)+2, SLD) } \
    f16x8 af0 = *(const f16x8*)&Alds[(t)&1][wave*16 + llo][lhi*8]; \
    f16x8 af1 = *(const f16x8*)&Alds[(t)&1][wave*16 + llo][32 + lhi*8]; \
    _Pragma("unroll") \
    for (int n=0;n<4;n++){ \
      acc[n] = __builtin_amdgcn_mfma_f32_16x16x32_f16(af0, wf[n*2],   acc[n], 0,0,0); \
      acc[n] = __builtin_amdgcn_mfma_f32_16x16x32_f16(af1, wf[n*2+1], acc[n], 0,0,0); \
    } \
    if ((t) < 15) { STOREA(((t)+1)&1, SST) } }

  #pragma unroll 1
  for (int t = 0; t < 16; t += 2){
    PROJ_ITER(t,   s0, s1)    // even t: A(t+2)->s0, store A(t+1) from s1
    PROJ_ITER(t+1, s1, s0)    // odd  t: A(t+2)->s1, store A(t+1) from s0
  }
#undef PROJ_ITER
#undef LOADA
#undef STOREA

  if (which < 2){
    const float scale = (which==0) ? 2.0f : 1.0f;   // fold dk=2.0 into q
    f16* dst = (which==0) ? qp : kp;
    #pragma unroll
    for (int n=0;n<4;n++)
      #pragma unroll
      for (int j=0;j<4;j++){
        long row = m0 + wave*16 + lhi*4 + j;
        dst[row*64 + 16*n + llo] = (f16)(acc[n][j]*scale);
      }
  } else {
    long row0 = m0 + wave*16 + lhi*4;
    long bh = row0 >> 11;
    long lr = row0 & 2047;
    #pragma unroll
    for (int n=0;n<4;n++){
      union { f16 h[4]; ushort4 u; } pk;
      #pragma unroll
      for (int j=0;j<4;j++) pk.h[j] = (f16)acc[n][j];
      *(ushort4*)&vpT[(bh*64 + 16*n + llo)*2048 + lr] = pk.u;
    }
  }
}

// ---------------- K2: flash attention with survivor-compacted threefry dropout
//                  + fused output projection (unchanged) ----------
__global__ __launch_bounds__(256) void flash_kernel(
    const f16* __restrict__ qp, const f16* __restrict__ kp, const f16* __restrict__ vpT,
    const f16* __restrict__ WoT, const float* __restrict__ bo, float* __restrict__ out)
{
  __shared__ __align__(16) f16 Klds[64][72];     // kv x dim; reused for O in epilogue
  __shared__ __align__(16) f16 Vlds[64][72];     // vdim x kv
  __shared__ __align__(16) f16 Plds[4][16][72];  // per-wave P (A-frag layout)
  __shared__ unsigned short Idl[4][1024];        // per-wave survivor id list
  const int tid = threadIdx.x;
  const int lane = tid & 63, wave = tid >> 6;
  const int llo = lane & 15, lhi = lane >> 4;
  const int bh = blockIdx.y;
  const int q0 = blockIdx.x * 64;

  const f16* qbase = qp + ((long)bh*2048 + q0 + wave*16 + llo)*64 + lhi*8;
  f16x8 qf0 = *(const f16x8*)qbase;
  f16x8 qf1 = *(const f16x8*)(qbase + 32);

  f32x4 O[4];
  float mrun[4], lrun[4];
  #pragma unroll
  for (int n=0;n<4;n++){ O[n][0]=0.f;O[n][1]=0.f;O[n][2]=0.f;O[n][3]=0.f; }
  #pragma unroll
  for (int j=0;j<4;j++){ mrun[j] = -__builtin_inff(); lrun[j]=0.f; }

  const int sr = tid >> 2;            // stage row 0..63
  const int sc = (tid & 3) * 16;      // stage col (f16)
  const f16* kbh = kp + (long)bh*2048*64;
  const f16* vbh = vpT + (long)bh*64*2048;
  uint32_t base_w = (uint32_t)((bh*2048 + q0 + wave*16)*2048);

  for (int kv0 = 0; kv0 < 2048; kv0 += 64, base_w += 64u){
    {
      const f16* src = kbh + (long)(kv0 + sr)*64 + sc;
      f16x8 t0 = *(const f16x8*)src;
      f16x8 t1 = *(const f16x8*)(src+8);
      *(f16x8*)&Klds[sr][sc]   = t0;
      *(f16x8*)&Klds[sr][sc+8] = t1;
      const f16* vsrc = vbh + (long)sr*2048 + kv0 + sc;
      f16x8 u0 = *(const f16x8*)vsrc;
      f16x8 u1 = *(const f16x8*)(vsrc+8);
      *(f16x8*)&Vlds[sr][sc]   = u0;
      *(f16x8*)&Vlds[sr][sc+8] = u1;
    }
    __syncthreads();

    f32x4 s[4];
    #pragma unroll
    for (int n=0;n<4;n++){ s[n][0]=0.f;s[n][1]=0.f;s[n][2]=0.f;s[n][3]=0.f; }
    #pragma unroll
    for (int n=0;n<4;n++){
      f16x8 kf0 = *(const f16x8*)&Klds[16*n+llo][lhi*8];
      s[n] = __builtin_amdgcn_mfma_f32_16x16x32_f16(qf0, kf0, s[n], 0,0,0);
      f16x8 kf1 = *(const f16x8*)&Klds[16*n+llo][32+lhi*8];
      s[n] = __builtin_amdgcn_mfma_f32_16x16x32_f16(qf1, kf1, s[n], 0,0,0);
    }
    float pmax[4];
    #pragma unroll
    for (int j=0;j<4;j++)
      pmax[j] = fmaxf(fmaxf(s[0][j],s[1][j]), fmaxf(s[2][j],s[3][j]));
    #pragma unroll
    for (int off=1; off<16; off<<=1){
      #pragma unroll
      for (int j=0;j<4;j++) pmax[j] = fmaxf(pmax[j], __shfl_xor(pmax[j], off));
    }
    float esc[4];
    #pragma unroll
    for (int j=0;j<4;j++){
      float mnew = fmaxf(mrun[j], pmax[j]);
      esc[j] = __expf(mrun[j] - mnew);
      mrun[j] = mnew;
    }
    float p[4][4]; float lsum[4] = {0.f,0.f,0.f,0.f};
    #pragma unroll
    for (int n=0;n<4;n++)
      #pragma unroll
      for (int j=0;j<4;j++){
        p[n][j] = __expf(s[n][j] - mrun[j]);
        lsum[j] += p[n][j];
      }
    #pragma unroll
    for (int off=1; off<16; off<<=1){
      #pragma unroll
      for (int j=0;j<4;j++) lsum[j] += __shfl_xor(lsum[j], off);
    }
    #pragma unroll
    for (int j=0;j<4;j++) lrun[j] = lrun[j]*esc[j] + lsum[j];
    #pragma unroll
    for (int n=0;n<4;n++)
      #pragma unroll
      for (int j=0;j<4;j++) O[n][j] *= esc[j];

    // ---- dropout via survivor compaction ----
    uint32_t cnt = 0;
    #pragma unroll
    for (int j=0;j<4;j++){
      #pragma unroll
      for (int n=0;n<4;n++){
        float pm = p[n][j]*(1.0f/0.9f);
        bool surv = pm > 0x1.0p-25f;            // (f16)pm != 0
        Plds[wave][lhi*4+j][16*n+llo] = (f16)pm;
        unsigned long long mk = __ballot(surv);
        if (mk){
          uint32_t pre = __builtin_amdgcn_mbcnt_hi((uint32_t)(mk>>32),
                         __builtin_amdgcn_mbcnt_lo((uint32_t)mk, 0u));
          if (surv)
            Idl[wave][cnt + pre] = (unsigned short)((j<<8)|(n<<6)|lane);
          cnt += (uint32_t)__builtin_popcountll(mk);
        }
      }
    }
    for (uint32_t pb = 0; pb < cnt; pb += 64){
      uint32_t idx = pb + (uint32_t)lane;
      if (idx < cnt){
        uint32_t id = (uint32_t)Idl[wave][idx];
        uint32_t jj = (id>>8)&3u, nn = (id>>6)&3u, ln = id & 63u;
        uint32_t i = base_w + (ln>>4)*8192u + jj*2048u + nn*16u + (ln&15u);
        uint32_t bits = tf_bits(i);
        if (bits >= 0xE6666600u)                 // uniform(bits) >= 0.9 -> drop
          Plds[wave][(ln>>4)*4+jj][16*nn+(ln&15u)] = (f16)0;
      }
    }

    f16x8 pa0 = *(const f16x8*)&Plds[wave][llo][lhi*8];
    f16x8 pa1 = *(const f16x8*)&Plds[wave][llo][32+lhi*8];
    #pragma unroll
    for (int n=0;n<4;n++){
      f16x8 vf0 = *(const f16x8*)&Vlds[16*n+llo][lhi*8];
      O[n] = __builtin_amdgcn_mfma_f32_16x16x32_f16(pa0, vf0, O[n], 0,0,0);
      f16x8 vf1 = *(const f16x8*)&Vlds[16*n+llo][32+lhi*8];
      O[n] = __builtin_amdgcn_mfma_f32_16x16x32_f16(pa1, vf1, O[n], 0,0,0);
    }
    __syncthreads();
  }

  // ---- fused epilogue: out[rows] = (O/l) @ Wo + bo, O staged f16 in Klds ----
  float rl[4];
  #pragma unroll
  for (int j=0;j<4;j++) rl[j] = 1.0f / lrun[j];
  #pragma unroll
  for (int n=0;n<4;n++)
    #pragma unroll
    for (int j=0;j<4;j++)
      Klds[wave*16 + lhi*4 + j][16*n + llo] = (f16)(O[n][j]*rl[j]);
  __syncthreads();

  f16x8 af0 = *(const f16x8*)&Klds[wave*16 + llo][lhi*8];
  f16x8 af1 = *(const f16x8*)&Klds[wave*16 + llo][32 + lhi*8];
  const long robase = (long)bh*2048 + q0 + wave*16 + lhi*4;
  for (int n0 = 0; n0 < 1024; n0 += 16){
    f16x8 b0 = *(const f16x8*)&WoT[(long)(n0+llo)*64 + lhi*8];
    f16x8 b1 = *(const f16x8*)&WoT[(long)(n0+llo)*64 + 32 + lhi*8];
    float bb = bo[n0+llo];
    f32x4 c; c[0]=bb; c[1]=bb; c[2]=bb; c[3]=bb;
    c = __builtin_amdgcn_mfma_f32_16x16x32_f16(af0, b0, c, 0,0,0);
    c = __builtin_amdgcn_mfma_f32_16x16x32_f16(af1, b1, c, 0,0,0);
    #pragma unroll
    for (int j=0;j<4;j++)
      out[(robase + j)*1024 + n0 + llo] = c[j];
  }
}

extern "C" void kernel_launch(void* const* d_in, const int* in_sizes, int n_in,
                              void* d_out, int out_size, void* d_ws, size_t ws_size,
                              hipStream_t stream){
  const float* query = (const float*)d_in[0];
  const float* key   = (const float*)d_in[1];
  const float* value = (const float*)d_in[2];
  const float* Wq = (const float*)d_in[3];
  const float* bq = (const float*)d_in[4];
  const float* Wk = (const float*)d_in[5];
  const float* bk = (const float*)d_in[6];
  const float* Wv = (const float*)d_in[7];
  const float* bv = (const float*)d_in[8];
  const float* Wo = (const float*)d_in[9];
  const float* bo = (const float*)d_in[10];
  float* out = (float*)d_out;

  char* ws = (char*)d_ws;
  f16* qp   = (f16*)(ws);                               // 4 MiB
  f16* kp   = (f16*)(ws + ((size_t)4<<20));             // 4 MiB
  f16* vpT  = (f16*)(ws + ((size_t)8<<20));             // 4 MiB
  f16* WoT  = (f16*)(ws + ((size_t)20<<20));            // 128 KiB
  f16* WqF  = (f16*)(ws + ((size_t)21<<20));            // 128 KiB
  f16* WkF  = (f16*)(ws + ((size_t)21<<20) + (256<<10));
  f16* WvF  = (f16*)(ws + ((size_t)21<<20) + (512<<10));

  wt_kernel<<<dim3(64), dim3(256), 0, stream>>>(Wq,Wk,Wv,Wo,WqF,WkF,WvF,WoT);
  proj_kernel<<<dim3(1536), dim3(256), 0, stream>>>(
      query,key,value,WqF,WkF,WvF,bq,bk,bv,qp,kp,vpT);
  flash_kernel<<<dim3(32,16), dim3(256), 0, stream>>>(qp,kp,vpT,WoT,bo,out);
}

// Round 10
// 247.726 us; speedup vs baseline: 1.1513x; 1.0670x over previous
//
#include <hip/hip_runtime.h>
#include <stdint.h>

typedef _Float16 f16;
typedef __attribute__((ext_vector_type(8))) _Float16 f16x8;
typedef __attribute__((ext_vector_type(4))) float f32x4;

// ---------------- threefry2x32 (JAX partitionable, key=(0,42), counts=(0,i)) ----
// returns w0 ^ w1 (JAX xor-fold for 32-bit draws). rotl forced to v_alignbit_b32.
__device__ __forceinline__ uint32_t rotl1(uint32_t x, uint32_t n){
  return __builtin_amdgcn_alignbit(x, x, 32u - n);
}
__device__ __forceinline__ uint32_t tf_bits(uint32_t i){
  const uint32_t ks1 = 42u, ks2 = 0x1BD11BDAu ^ 42u;
  uint32_t x0 = 0u, x1 = i + 42u;
#define R4(a,b,c,d) \
  x0 += x1; x1 = rotl1(x1,a); x1 ^= x0; \
  x0 += x1; x1 = rotl1(x1,b); x1 ^= x0; \
  x0 += x1; x1 = rotl1(x1,c); x1 ^= x0; \
  x0 += x1; x1 = rotl1(x1,d); x1 ^= x0;
  R4(13,15,26,6)  x0 += ks1; x1 += ks2 + 1u;
  R4(17,29,16,24) x0 += ks2; x1 += 2u;         // ks0 = 0
  R4(13,15,26,6)               x1 += ks1 + 3u; // x0 += ks0 = +0
  R4(17,29,16,24) x0 += ks1; x1 += ks2 + 4u;
  R4(13,15,26,6)  x0 += ks2; x1 += 5u;         // ks0 = 0
#undef R4
  return x0 ^ x1;
}

// ---------------- K1 (A/B template): R4-exact projections ----------------
// Variant A (PACKED=0): blocks [0,256) = WoT transpose role; [256,1024) = proj
//   tiles p in [0,768), scalar f16 LDS stores (the R4-original code path).
// Variant B (PACKED=1): 768 blocks = proj tiles p in [768,1536), single f16x8
//   LDS store (the R6+ code path). Everything else byte-identical.
template<int PACKED>
__global__ __launch_bounds__(256) void proj_kernel(
    const float* __restrict__ query, const float* __restrict__ keyp, const float* __restrict__ value,
    const float* __restrict__ Wq, const float* __restrict__ bq,
    const float* __restrict__ Wk, const float* __restrict__ bk,
    const float* __restrict__ Wv, const float* __restrict__ bv,
    const float* __restrict__ Wo,
    f16* __restrict__ qp, f16* __restrict__ kp, f16* __restrict__ vpT,
    f16* __restrict__ WoT)
{
  __shared__ __align__(16) f16 Alds[64][40];   // rows x k (80B stride)
  __shared__ __align__(16) f16 Wlds[64][40];   // [col][k]
  const int bid = blockIdx.x;
  const int tid = threadIdx.x;
  const int lane = tid & 63, wave = tid >> 6;
  const int llo = lane & 15, lhi = lane >> 4;

  int p;
  if (PACKED == 0){
    if (bid < 256){
      // ---- WoT role ----
      int t = bid*256 + tid;
      int n = t & 1023, k = t >> 10;
      WoT[(long)n*64 + k] = (f16)Wo[(long)k*1024 + n];
      return;
    }
    p = bid - 256;            // [0,768)
  } else {
    p = 768 + bid;            // [768,1536)
  }

  const int which = p >> 9;           // 0..2
  const long m0 = (long)(p & 511) * 64;
  const float* A    = which==0 ? query : (which==1 ? keyp : value);
  const float* W    = which==0 ? Wq    : (which==1 ? Wk   : Wv);
  const float* bias = which==0 ? bq    : (which==1 ? bk   : bv);

  f32x4 acc[4];
  #pragma unroll
  for (int n=0;n<4;n++){
    float bb = bias[16*n + llo];
    acc[n][0]=bb; acc[n][1]=bb; acc[n][2]=bb; acc[n][3]=bb;
  }

  const int ar = tid >> 2;            // 0..63
  const int ac = (tid & 3) * 8;
  const int wcol = tid & 63;
  const int wk = (tid >> 6) * 8;

  for (int k0 = 0; k0 < 1024; k0 += 32){
    {
      const float* asrc = A + (m0 + ar)*1024 + k0 + ac;
      float4 v0 = *(const float4*)asrc;
      float4 v1 = *(const float4*)(asrc + 4);
      if (PACKED == 0){
        f16* ad = &Alds[ar][ac];
        ad[0]=(f16)v0.x; ad[1]=(f16)v0.y; ad[2]=(f16)v0.z; ad[3]=(f16)v0.w;
        ad[4]=(f16)v1.x; ad[5]=(f16)v1.y; ad[6]=(f16)v1.z; ad[7]=(f16)v1.w;
      } else {
        union { f16 h[8]; f16x8 v; } aw;
        aw.h[0]=(f16)v0.x; aw.h[1]=(f16)v0.y; aw.h[2]=(f16)v0.z; aw.h[3]=(f16)v0.w;
        aw.h[4]=(f16)v1.x; aw.h[5]=(f16)v1.y; aw.h[6]=(f16)v1.z; aw.h[7]=(f16)v1.w;
        *(f16x8*)&Alds[ar][ac] = aw.v;
      }
      f16 wt[8];
      #pragma unroll
      for (int j=0;j<8;j++) wt[j] = (f16)W[(long)(k0+wk+j)*64 + wcol];
      *(f16x8*)&Wlds[wcol][wk] = *(f16x8*)wt;
    }
    __syncthreads();
    f16x8 af = *(const f16x8*)&Alds[wave*16 + llo][lhi*8];
    #pragma unroll
    for (int n=0;n<4;n++){
      f16x8 bf = *(const f16x8*)&Wlds[16*n + llo][lhi*8];
      acc[n] = __builtin_amdgcn_mfma_f32_16x16x32_f16(af, bf, acc[n], 0,0,0);
    }
    __syncthreads();
  }

  if (which < 2){
    const float scale = (which==0) ? 2.0f : 1.0f;   // fold dk=2.0 into q
    f16* dst = (which==0) ? qp : kp;
    #pragma unroll
    for (int n=0;n<4;n++)
      #pragma unroll
      for (int j=0;j<4;j++){
        long row = m0 + wave*16 + lhi*4 + j;
        dst[row*64 + 16*n + llo] = (f16)(acc[n][j]*scale);
      }
  } else {
    long row0 = m0 + wave*16 + lhi*4;
    long bh = row0 >> 11;
    long lr = row0 & 2047;
    #pragma unroll
    for (int n=0;n<4;n++){
      union { f16 h[4]; ushort4 u; } pk;
      #pragma unroll
      for (int j=0;j<4;j++) pk.h[j] = (f16)acc[n][j];
      *(ushort4*)&vpT[(bh*64 + 16*n + llo)*2048 + lr] = pk.u;
    }
  }
}

// ---------------- K2: flash attention with survivor-compacted threefry dropout
//                  + fused output projection (unchanged) ----------
__global__ __launch_bounds__(256) void flash_kernel(
    const f16* __restrict__ qp, const f16* __restrict__ kp, const f16* __restrict__ vpT,
    const f16* __restrict__ WoT, const float* __restrict__ bo, float* __restrict__ out)
{
  __shared__ __align__(16) f16 Klds[64][72];     // kv x dim; reused for O in epilogue
  __shared__ __align__(16) f16 Vlds[64][72];     // vdim x kv
  __shared__ __align__(16) f16 Plds[4][16][72];  // per-wave P (A-frag layout)
  __shared__ unsigned short Idl[4][1024];        // per-wave survivor id list
  const int tid = threadIdx.x;
  const int lane = tid & 63, wave = tid >> 6;
  const int llo = lane & 15, lhi = lane >> 4;
  const int bh = blockIdx.y;
  const int q0 = blockIdx.x * 64;

  const f16* qbase = qp + ((long)bh*2048 + q0 + wave*16 + llo)*64 + lhi*8;
  f16x8 qf0 = *(const f16x8*)qbase;
  f16x8 qf1 = *(const f16x8*)(qbase + 32);

  f32x4 O[4];
  float mrun[4], lrun[4];
  #pragma unroll
  for (int n=0;n<4;n++){ O[n][0]=0.f;O[n][1]=0.f;O[n][2]=0.f;O[n][3]=0.f; }
  #pragma unroll
  for (int j=0;j<4;j++){ mrun[j] = -__builtin_inff(); lrun[j]=0.f; }

  const int sr = tid >> 2;            // stage row 0..63
  const int sc = (tid & 3) * 16;      // stage col (f16)
  const f16* kbh = kp + (long)bh*2048*64;
  const f16* vbh = vpT + (long)bh*64*2048;
  uint32_t base_w = (uint32_t)((bh*2048 + q0 + wave*16)*2048);

  for (int kv0 = 0; kv0 < 2048; kv0 += 64, base_w += 64u){
    {
      const f16* src = kbh + (long)(kv0 + sr)*64 + sc;
      f16x8 t0 = *(const f16x8*)src;
      f16x8 t1 = *(const f16x8*)(src+8);
      *(f16x8*)&Klds[sr][sc]   = t0;
      *(f16x8*)&Klds[sr][sc+8] = t1;
      const f16* vsrc = vbh + (long)sr*2048 + kv0 + sc;
      f16x8 u0 = *(const f16x8*)vsrc;
      f16x8 u1 = *(const f16x8*)(vsrc+8);
      *(f16x8*)&Vlds[sr][sc]   = u0;
      *(f16x8*)&Vlds[sr][sc+8] = u1;
    }
    __syncthreads();

    f32x4 s[4];
    #pragma unroll
    for (int n=0;n<4;n++){ s[n][0]=0.f;s[n][1]=0.f;s[n][2]=0.f;s[n][3]=0.f; }
    #pragma unroll
    for (int n=0;n<4;n++){
      f16x8 kf0 = *(const f16x8*)&Klds[16*n+llo][lhi*8];
      s[n] = __builtin_amdgcn_mfma_f32_16x16x32_f16(qf0, kf0, s[n], 0,0,0);
      f16x8 kf1 = *(const f16x8*)&Klds[16*n+llo][32+lhi*8];
      s[n] = __builtin_amdgcn_mfma_f32_16x16x32_f16(qf1, kf1, s[n], 0,0,0);
    }
    float pmax[4];
    #pragma unroll
    for (int j=0;j<4;j++)
      pmax[j] = fmaxf(fmaxf(s[0][j],s[1][j]), fmaxf(s[2][j],s[3][j]));
    #pragma unroll
    for (int off=1; off<16; off<<=1){
      #pragma unroll
      for (int j=0;j<4;j++) pmax[j] = fmaxf(pmax[j], __shfl_xor(pmax[j], off));
    }
    float esc[4];
    #pragma unroll
    for (int j=0;j<4;j++){
      float mnew = fmaxf(mrun[j], pmax[j]);
      esc[j] = __expf(mrun[j] - mnew);
      mrun[j] = mnew;
    }
    float p[4][4]; float lsum[4] = {0.f,0.f,0.f,0.f};
    #pragma unroll
    for (int n=0;n<4;n++)
      #pragma unroll
      for (int j=0;j<4;j++){
        p[n][j] = __expf(s[n][j] - mrun[j]);
        lsum[j] += p[n][j];
      }
    #pragma unroll
    for (int off=1; off<16; off<<=1){
      #pragma unroll
      for (int j=0;j<4;j++) lsum[j] += __shfl_xor(lsum[j], off);
    }
    #pragma unroll
    for (int j=0;j<4;j++) lrun[j] = lrun[j]*esc[j] + lsum[j];
    #pragma unroll
    for (int n=0;n<4;n++)
      #pragma unroll
      for (int j=0;j<4;j++) O[n][j] *= esc[j];

    // ---- dropout via survivor compaction ----
    uint32_t cnt = 0;
    #pragma unroll
    for (int j=0;j<4;j++){
      #pragma unroll
      for (int n=0;n<4;n++){
        float pm = p[n][j]*(1.0f/0.9f);
        bool surv = pm > 0x1.0p-25f;            // (f16)pm != 0
        Plds[wave][lhi*4+j][16*n+llo] = (f16)pm;
        unsigned long long mk = __ballot(surv);
        if (mk){
          uint32_t pre = __builtin_amdgcn_mbcnt_hi((uint32_t)(mk>>32),
                         __builtin_amdgcn_mbcnt_lo((uint32_t)mk, 0u));
          if (surv)
            Idl[wave][cnt + pre] = (unsigned short)((j<<8)|(n<<6)|lane);
          cnt += (uint32_t)__builtin_popcountll(mk);
        }
      }
    }
    for (uint32_t pb = 0; pb < cnt; pb += 64){
      uint32_t idx = pb + (uint32_t)lane;
      if (idx < cnt){
        uint32_t id = (uint32_t)Idl[wave][idx];
        uint32_t jj = (id>>8)&3u, nn = (id>>6)&3u, ln = id & 63u;
        uint32_t i = base_w + (ln>>4)*8192u + jj*2048u + nn*16u + (ln&15u);
        uint32_t bits = tf_bits(i);
        if (bits >= 0xE6666600u)                 // uniform(bits) >= 0.9 -> drop
          Plds[wave][(ln>>4)*4+jj][16*nn+(ln&15u)] = (f16)0;
      }
    }

    f16x8 pa0 = *(const f16x8*)&Plds[wave][llo][lhi*8];
    f16x8 pa1 = *(const f16x8*)&Plds[wave][llo][32+lhi*8];
    #pragma unroll
    for (int n=0;n<4;n++){
      f16x8 vf0 = *(const f16x8*)&Vlds[16*n+llo][lhi*8];
      O[n] = __builtin_amdgcn_mfma_f32_16x16x32_f16(pa0, vf0, O[n], 0,0,0);
      f16x8 vf1 = *(const f16x8*)&Vlds[16*n+llo][32+lhi*8];
      O[n] = __builtin_amdgcn_mfma_f32_16x16x32_f16(pa1, vf1, O[n], 0,0,0);
    }
    __syncthreads();
  }

  // ---- fused epilogue: out[rows] = (O/l) @ Wo + bo, O staged f16 in Klds ----
  float rl[4];
  #pragma unroll
  for (int j=0;j<4;j++) rl[j] = 1.0f / lrun[j];
  #pragma unroll
  for (int n=0;n<4;n++)
    #pragma unroll
    for (int j=0;j<4;j++)
      Klds[wave*16 + lhi*4 + j][16*n + llo] = (f16)(O[n][j]*rl[j]);
  __syncthreads();

  f16x8 af0 = *(const f16x8*)&Klds[wave*16 + llo][lhi*8];
  f16x8 af1 = *(const f16x8*)&Klds[wave*16 + llo][32 + lhi*8];
  const long robase = (long)bh*2048 + q0 + wave*16 + lhi*4;
  for (int n0 = 0; n0 < 1024; n0 += 16){
    f16x8 b0 = *(const f16x8*)&WoT[(long)(n0+llo)*64 + lhi*8];
    f16x8 b1 = *(const f16x8*)&WoT[(long)(n0+llo)*64 + 32 + lhi*8];
    float bb = bo[n0+llo];
    f32x4 c; c[0]=bb; c[1]=bb; c[2]=bb; c[3]=bb;
    c = __builtin_amdgcn_mfma_f32_16x16x32_f16(af0, b0, c, 0,0,0);
    c = __builtin_amdgcn_mfma_f32_16x16x32_f16(af1, b1, c, 0,0,0);
    #pragma unroll
    for (int j=0;j<4;j++)
      out[(robase + j)*1024 + n0 + llo] = c[j];
  }
}

extern "C" void kernel_launch(void* const* d_in, const int* in_sizes, int n_in,
                              void* d_out, int out_size, void* d_ws, size_t ws_size,
                              hipStream_t stream){
  const float* query = (const float*)d_in[0];
  const float* key   = (const float*)d_in[1];
  const float* value = (const float*)d_in[2];
  const float* Wq = (const float*)d_in[3];
  const float* bq = (const float*)d_in[4];
  const float* Wk = (const float*)d_in[5];
  const float* bk = (const float*)d_in[6];
  const float* Wv = (const float*)d_in[7];
  const float* bv = (const float*)d_in[8];
  const float* Wo = (const float*)d_in[9];
  const float* bo = (const float*)d_in[10];
  float* out = (float*)d_out;

  char* ws = (char*)d_ws;
  f16* qp   = (f16*)(ws);                               // 4 MiB
  f16* kp   = (f16*)(ws + ((size_t)4<<20));             // 4 MiB
  f16* vpT  = (f16*)(ws + ((size_t)8<<20));             // 4 MiB
  f16* WoT  = (f16*)(ws + ((size_t)20<<20));            // 128 KiB

  // A/B: variant 0 = R4-exact scalar LDS stores (+WoT role), variant 1 = packed
  proj_kernel<0><<<dim3(1024), dim3(256), 0, stream>>>(
      query,key,value,Wq,bq,Wk,bk,Wv,bv,Wo,qp,kp,vpT,WoT);
  proj_kernel<1><<<dim3(768), dim3(256), 0, stream>>>(
      query,key,value,Wq,bq,Wk,bk,Wv,bv,Wo,qp,kp,vpT,WoT);
  flash_kernel<<<dim3(32,16), dim3(256), 0, stream>>>(qp,kp,vpT,WoT,bo,out);
}